// Round 2
// baseline (99.201 us; speedup 1.0000x reference)
//
#include <hip/hip_runtime.h>

// ChamferLoss: B=4, N=M=8192, D=3, fp32.
// loss = mean_b[ mean(pred2gt) + mean(gt2pred) + max(pred2gt) ]
// R10: R9 (prefetch pipeline, fused pmin-init, uint4 reduce) + explicit 2-pair
//      unroll of the hot loop with ping-pong register buffers -> no v_mov
//      rotate on the load-use path, loads always exactly 1 pair ahead.
// R8 baseline 85.9us. MFMA floor: 524,288 x 32x32x16 bf16 @ ~8cyc/CU = 6.9us;
// VALU floor ~3.4us (v_min3). Gap = latency/overhead, attacked here.
//   A row m (K=16): [xh0..2, xh0..2, xl0..2, 1, 1, 0...]
//   B col n (K=16): [-2yh0..2, -2yl0..2, -2yh0..2, y2h, y2l, 0]
//   D = y2 - 2(xh.yh + xh.yl + xl.yh); d2 = x2 + min_y D  (xl.yl ~2^-18 dropped)

typedef short  s16x8  __attribute__((ext_vector_type(8)));
typedef float  f32x16 __attribute__((ext_vector_type(16)));

#define BATCH 4
#define NPTS  8192
#define TPB   256
#define YS    4                    // y slices per (b,dir)
#define YTILES (NPTS / 32)         // 256 y-tiles total
#define YTS   (YTILES / YS)        // 64 y-tiles per slice
#define XPB   256                  // x per block: 4 waves x 2 tiles x 32
#define NXC   (NPTS / XPB)         // 32

__device__ __forceinline__ unsigned int bft(float f) { return __float_as_uint(f) >> 16; }
__device__ __forceinline__ float bfv(unsigned int s) { return __uint_as_float(s << 16); }

// Precompute B-frags: bfrag[arr(2)][b(4)][tile(256)][half(2)][n(32)] x uint4.
// Also initializes pmin[gid] (1:1 thread->entry) so no separate memset dispatch.
__global__ __launch_bounds__(TPB)
void yprep(const float* __restrict__ pred, const float* __restrict__ gt,
           uint4* __restrict__ bfrag, unsigned int* __restrict__ pmin) {
    const int gid = blockIdx.x * TPB + threadIdx.x;    // 0..65535
    pmin[gid] = 0xFFFFFFFFu;                           // +inf pattern for atomicMin
    const int arr = gid >> 15;                         // 0=pred, 1=gt
    const int rem = gid & 32767;                       // b*NPTS + yi
    const int yi  = rem & (NPTS - 1);
    const float* y = (arr ? gt : pred) + (size_t)rem * 3;
    const float a0 = y[0], a1 = y[1], a2 = y[2];
    const unsigned int yh0 = bft(a0), yh1 = bft(a1), yh2 = bft(a2);
    const float l0 = a0 - bfv(yh0), l1 = a1 - bfv(yh1), l2 = a2 - bfv(yh2);
    const unsigned int nh0 = bft(-2.f * bfv(yh0));     // exact in bf16
    const unsigned int nh1 = bft(-2.f * bfv(yh1));
    const unsigned int nh2 = bft(-2.f * bfv(yh2));
    const unsigned int nl0 = bft(-2.f * l0), nl1 = bft(-2.f * l1), nl2 = bft(-2.f * l2);
    const float y2 = a0 * a0 + a1 * a1 + a2 * a2;
    const unsigned int q2h = bft(y2);
    const unsigned int q2l = bft(y2 - bfv(q2h));
    uint4 w0, w1;                                      // k-order halves
    w0.x = nh0 | (nh1 << 16);
    w0.y = nh2 | (nl0 << 16);
    w0.z = nl1 | (nl2 << 16);
    w0.w = nh0 | (nh1 << 16);
    w1.x = nh2 | (q2h << 16);
    w1.y = q2l;
    w1.z = 0u; w1.w = 0u;
    const size_t base = ((size_t)(gid >> 13) * YTILES + (yi >> 5)) * 64;  // (arr*4+b)
    bfrag[base + (yi & 31)]      = w0;
    bfrag[base + 32 + (yi & 31)] = w1;
}

__global__ __launch_bounds__(TPB, 4)
void nn_mfma(const float* __restrict__ pred, const float* __restrict__ gt,
             const uint4* __restrict__ bfrag, unsigned int* __restrict__ pmin) {
    const int xc = blockIdx.x, sl = blockIdx.y, bd = blockIdx.z;
    const int b = bd >> 1, dir = bd & 1;
    const float* xp = (dir ? gt : pred) + (size_t)b * NPTS * 3;
    const int yarr = dir ? 0 : 1;                      // y = dir ? pred : gt
    const uint4* bfb = bfrag + (size_t)(yarr * BATCH + b) * YTILES * 64;

    const int t = threadIdx.x;
    const int w = t >> 6, l = t & 63;
    const int m32 = l & 31, hh = l >> 5;
    const int xbase = xc * XPB + w * 64;

    // A-frags + x2 for the wave's two 32-row x-tiles.
    s16x8 af[2];
    float x2j[2];
    #pragma unroll
    for (int j = 0; j < 2; ++j) {
        const int xi = xbase + j * 32 + m32;
        const float c0 = xp[xi * 3], c1 = xp[xi * 3 + 1], c2 = xp[xi * 3 + 2];
        x2j[j] = c0 * c0 + c1 * c1 + c2 * c2;
        const unsigned int xh0 = bft(c0), xh1 = bft(c1), xh2 = bft(c2);
        const unsigned int xl0 = bft(c0 - bfv(xh0));
        const unsigned int xl1 = bft(c1 - bfv(xh1));
        const unsigned int xl2 = bft(c2 - bfv(xh2));
        s16x8 a;                                       // k = hh*8 + e
        a[0] = (short)(hh ? xl2 : xh0);
        a[1] = (short)(hh ? 0x3F80u : xh1);            // 1.0 bf16 (y2h)
        a[2] = (short)(hh ? 0x3F80u : xh2);            // 1.0 bf16 (y2l)
        a[3] = (short)(hh ? 0u : xh0);
        a[4] = (short)(hh ? 0u : xh1);
        a[5] = (short)(hh ? 0u : xh2);
        a[6] = (short)(hh ? 0u : xl0);
        a[7] = (short)(hh ? 0u : xl1);
        af[j] = a;
    }

    f32x16 zero, mn0, mn1;
    #pragma unroll
    for (int r = 0; r < 16; ++r) { zero[r] = 0.f; mn0[r] = 3.4e38f; mn1[r] = 3.4e38f; }

    // Hot loop, software-pipelined + 2-pair unrolled (ping-pong buffers, no
    // register rotate). Per pair: 2 coalesced 1KB loads + 4 MFMA + 32 v_min3.
    // Loads are always exactly one pair ahead of the MFMAs consuming them.
#define PAIR_COMPUTE(P0, P1)                                                          \
    do {                                                                              \
        const s16x8 bf0 = __builtin_bit_cast(s16x8, (P0));                            \
        const s16x8 bf1 = __builtin_bit_cast(s16x8, (P1));                            \
        const f32x16 e00 = __builtin_amdgcn_mfma_f32_32x32x16_bf16(af[0], bf0, zero, 0, 0, 0); \
        const f32x16 e01 = __builtin_amdgcn_mfma_f32_32x32x16_bf16(af[0], bf1, zero, 0, 0, 0); \
        mn0 = __builtin_elementwise_min(mn0, __builtin_elementwise_min(e00, e01));    \
        const f32x16 e10 = __builtin_amdgcn_mfma_f32_32x32x16_bf16(af[1], bf0, zero, 0, 0, 0); \
        const f32x16 e11 = __builtin_amdgcn_mfma_f32_32x32x16_bf16(af[1], bf1, zero, 0, 0, 0); \
        mn1 = __builtin_elementwise_min(mn1, __builtin_elementwise_min(e10, e11));    \
    } while (0)

    const uint4* bp = bfb + (size_t)(sl * YTS) * 64 + l;
    uint4 a0 = bp[0], a1 = bp[64];                     // pair 0
    for (int it = 0; it < YTS / 4 - 1; ++it) {         // 15 outer iters
        bp += 128;
        const uint4 b0 = bp[0], b1 = bp[64];           // load odd pair
        PAIR_COMPUTE(a0, a1);                          // compute even pair
        bp += 128;
        a0 = bp[0]; a1 = bp[64];                       // load next even pair
        PAIR_COMPUTE(b0, b1);                          // compute odd pair
    }
    {   // pairs 30, 31
        bp += 128;
        const uint4 b0 = bp[0], b1 = bp[64];
        PAIR_COMPUTE(a0, a1);
        PAIR_COMPUTE(b0, b1);
    }
#undef PAIR_COMPUTE

    // Butterfly min across the 32 cols (stays within each 32-lane half).
    #pragma unroll
    for (int off = 16; off; off >>= 1) {
        #pragma unroll
        for (int r = 0; r < 16; ++r) {
            mn0[r] = fminf(mn0[r], __shfl_xor(mn0[r], off, 64));
            mn1[r] = fminf(mn1[r], __shfl_xor(mn1[r], off, 64));
        }
    }

    // Lane l: r = l&15; lanes (l&31)<16 -> tile0, else tile1. One atomic/lane.
    const int r = l & 15;
    const int row = (r & 3) + 8 * (r >> 2) + 4 * hh;   // C/D row map (m74/m101)
    float v0 = mn0[0], v1 = mn1[0];
    #pragma unroll
    for (int rr = 1; rr < 16; ++rr) {
        v0 = (r == rr) ? mn0[rr] : v0;
        v1 = (r == rr) ? mn1[rr] : v1;
    }
    const float x20 = __shfl(x2j[0], row, 64);
    const float x21 = __shfl(x2j[1], row, 64);
    const bool g1 = (l & 31) >= 16;
    const float d = fmaxf((g1 ? v1 : v0) + (g1 ? x21 : x20), 0.f);
    const int xpt = xbase + (g1 ? 32 : 0) + row;
    atomicMin(&pmin[(size_t)bd * NPTS + xpt], __float_as_uint(d));
}

// One 1024-thread block: 128 threads per bd; sum + max per bd; write out[0].
__global__ __launch_bounds__(1024)
void reduce_all(const unsigned int* __restrict__ pmin, float* __restrict__ out) {
    const int t  = threadIdx.x;
    const int bd = t >> 7;
    const int l  = t & 127;
    const uint4* base = (const uint4*)(pmin + (size_t)bd * NPTS);  // 2048 uint4/bd
    float sum = 0.f, mx = -1.f;
    #pragma unroll
    for (int i = 0; i < NPTS / 128 / 4; ++i) {         // 16 x 2KB coalesced
        const uint4 q = base[i * 128 + l];
        const float f0 = __uint_as_float(q.x), f1 = __uint_as_float(q.y);
        const float f2 = __uint_as_float(q.z), f3 = __uint_as_float(q.w);
        sum += (f0 + f1) + (f2 + f3);
        mx = fmaxf(mx, fmaxf(fmaxf(f0, f1), fmaxf(f2, f3)));
    }
    #pragma unroll
    for (int off = 32; off; off >>= 1) {
        sum += __shfl_down(sum, off, 64);
        mx = fmaxf(mx, __shfl_down(mx, off, 64));
    }
    __shared__ float ss[16], sm[16];
    if ((t & 63) == 0) { ss[t >> 6] = sum; sm[t >> 6] = mx; }
    __syncthreads();
    if (t == 0) {
        float acc = 0.f;
        #pragma unroll
        for (int d = 0; d < 8; ++d) {
            const float S = ss[2 * d] + ss[2 * d + 1];
            const float M = fmaxf(sm[2 * d], sm[2 * d + 1]);
            acc += S * (1.f / NPTS) + ((d & 1) ? 0.f : M);   // max only for pred2gt
        }
        out[0] = acc * (1.f / BATCH);
    }
}

extern "C" void kernel_launch(void* const* d_in, const int* in_sizes, int n_in,
                              void* d_out, int out_size, void* d_ws, size_t ws_size,
                              hipStream_t stream) {
    const float* pred = (const float*)d_in[0];
    const float* gt   = (const float*)d_in[1];

    unsigned int* pmin = (unsigned int*)d_ws;                       // 256 KB
    uint4* bfrag = (uint4*)((char*)d_ws + (size_t)2 * BATCH * NPTS * 4);  // 2 MB

    yprep<<<dim3(2 * BATCH * NPTS / TPB), TPB, 0, stream>>>(pred, gt, bfrag, pmin);
    dim3 g1(NXC, YS, 2 * BATCH);   // 32 x 4 x 8 = 1024 blocks (4/CU)
    nn_mfma<<<g1, TPB, 0, stream>>>(pred, gt, bfrag, pmin);
    reduce_all<<<dim3(1), 1024, 0, stream>>>(pmin, (float*)d_out);
}